// Round 1
// baseline (122.334 us; speedup 1.0000x reference)
//
#include <hip/hip_runtime.h>

#define BATCH 8
#define CH 64
#define CIN 3
#define HIN 224
#define WIN 224
#define KSZ 5
#define STRIDE 2
#define HO 110
#define WO 110

__global__ __launch_bounds__(256) void conv5x5_g_kernel(
    const float* __restrict__ x,
    const float* __restrict__ Wt,
    float* __restrict__ out)
{
    __shared__ float wsh[CIN * KSZ * KSZ];  // 75 floats

    const int bc = blockIdx.y;            // b*CH + c
    const int c = bc & (CH - 1);          // CH=64 power of 2

    // cooperative weight load (uniform per block)
    if (threadIdx.x < CIN * KSZ * KSZ) {
        wsh[threadIdx.x] = Wt[c * (CIN * KSZ * KSZ) + threadIdx.x];
    }
    __syncthreads();

    const int plane = HO * WO;            // 12100
    const int idx = blockIdx.x * blockDim.x + threadIdx.x;
    if (idx >= plane) return;

    const int ho = idx / WO;
    const int wo = idx - ho * WO;
    const int ih0 = ho * STRIDE;
    const int iw0 = wo * STRIDE;

    const float* xb = x + (size_t)bc * CIN * HIN * WIN;
    float acc = 0.0f;

#pragma unroll
    for (int ci = 0; ci < CIN; ++ci) {
        const float* xp = xb + (size_t)ci * HIN * WIN + ih0 * WIN + iw0;
        const float* wp = wsh + ci * KSZ * KSZ;
#pragma unroll
        for (int kh = 0; kh < KSZ; ++kh) {
#pragma unroll
            for (int kw = 0; kw < KSZ; ++kw) {
                acc = fmaf(xp[kh * WIN + kw], wp[kh * KSZ + kw], acc);
            }
        }
    }

    out[(size_t)bc * plane + idx] = acc;
}

extern "C" void kernel_launch(void* const* d_in, const int* in_sizes, int n_in,
                              void* d_out, int out_size, void* d_ws, size_t ws_size,
                              hipStream_t stream)
{
    const float* x = (const float*)d_in[0];
    const float* Wt = (const float*)d_in[1];
    float* out = (float*)d_out;

    const int plane = HO * WO;                       // 12100
    dim3 block(256);
    dim3 grid((plane + 255) / 256, BATCH * CH);      // 48 x 512

    conv5x5_g_kernel<<<grid, block, 0, stream>>>(x, Wt, out);
}

// Round 2
// 83.441 us; speedup vs baseline: 1.4661x; 1.4661x over previous
//
#include <hip/hip_runtime.h>

#define BATCH 8
#define CH 64
#define CIN 3
#define HIN 224
#define WIN 224
#define KSZ 5
#define STRIDE 2
#define HO 110
#define WO 110
#define RY 5
#define GROUPS (HO / RY)                  // 22
#define ITEMS (GROUPS * WO)               // 2420
#define BLOCKS_X ((ITEMS + 255) / 256)    // 10
#define NPLANES (BATCH * CH)              // 512
#define NWG (BLOCKS_X * NPLANES)          // 5120 (divisible by 8 -> bijective swizzle)
#define NROWS (2 * (RY - 1) + KSZ)        // 13 input rows per thread

// 8-byte-aligned float4 (element offset is always even -> 8B alignment guaranteed)
typedef float float4u __attribute__((ext_vector_type(4), aligned(8)));

__global__ __launch_bounds__(256) void conv5_reg_kernel(
    const float* __restrict__ x,
    const float* __restrict__ Wt,
    float* __restrict__ out)
{
    __shared__ float wsh[CIN * KSZ * KSZ];  // 75 floats

    // ---- flatten + XCD-aware swizzle: all 10 x-blocks of a plane -> same XCD ----
    const int wg = blockIdx.x;               // 1-D grid of NWG
    const int per = NWG >> 3;                // 640 blocks per XCD chunk
    const int swz = (wg & 7) * per + (wg >> 3);
    const int bc   = swz / BLOCKS_X;         // which (b,c) plane
    const int xblk = swz - bc * BLOCKS_X;    // block within plane
    const int c = bc & (CH - 1);

    const int tid = threadIdx.x;
    if (tid < CIN * KSZ * KSZ) {
        wsh[tid] = Wt[c * (CIN * KSZ * KSZ) + tid];
    }
    __syncthreads();

    const int idx = xblk * 256 + tid;
    if (idx >= ITEMS) return;

    const int wo  = idx % WO;
    const int g   = idx / WO;
    const int ho0 = g * RY;
    const int ih0 = ho0 * STRIDE;
    const int iw0 = wo * STRIDE;

    float acc[RY] = {0.f, 0.f, 0.f, 0.f, 0.f};

    const float* xb = x + (size_t)bc * (CIN * HIN * WIN);

#pragma unroll
    for (int ci = 0; ci < CIN; ++ci) {
        // stage this ci's 25 weights LDS -> registers (broadcast reads, done once)
        float wr[KSZ * KSZ];
#pragma unroll
        for (int i = 0; i < KSZ * KSZ; ++i) wr[i] = wsh[ci * KSZ * KSZ + i];

        const float* xp = xb + (size_t)ci * HIN * WIN + (size_t)ih0 * WIN + iw0;
#pragma unroll
        for (int r = 0; r < NROWS; ++r) {   // 13 rows feed 5 vertical outputs
            const float* rp = xp + r * WIN;
            float4u v4 = *reinterpret_cast<const float4u*>(rp);
            float   v5 = rp[4];
            float xv[KSZ] = {v4.x, v4.y, v4.z, v4.w, v5};
#pragma unroll
            for (int t = 0; t < RY; ++t) {
                const int kh = r - STRIDE * t;
                if (kh >= 0 && kh < KSZ) {
#pragma unroll
                    for (int kw = 0; kw < KSZ; ++kw) {
                        acc[t] = fmaf(xv[kw], wr[kh * KSZ + kw], acc[t]);
                    }
                }
            }
        }
    }

    float* op = out + (size_t)bc * (HO * WO) + (size_t)ho0 * WO + wo;
#pragma unroll
    for (int t = 0; t < RY; ++t) {
        op[t * WO] = acc[t];
    }
}

extern "C" void kernel_launch(void* const* d_in, const int* in_sizes, int n_in,
                              void* d_out, int out_size, void* d_ws, size_t ws_size,
                              hipStream_t stream)
{
    const float* x  = (const float*)d_in[0];
    const float* Wt = (const float*)d_in[1];
    float* out = (float*)d_out;

    conv5_reg_kernel<<<dim3(NWG), dim3(256), 0, stream>>>(x, Wt, out);
}